// Round 11
// baseline (134.177 us; speedup 1.0000x reference)
//
#include <hip/hip_runtime.h>
#include <cstdint>
#include <cstddef>

using u32 = unsigned int;
using u64 = unsigned long long;

typedef int v4i  __attribute__((ext_vector_type(4)));
typedef int v16i __attribute__((ext_vector_type(16)));

#define EPSV 1e-5f

// ---------------------------------------------------------------------------
// Kernel 1: weight prep. One block per (co, conv). 256 threads = 256 in-chans.
// Wsgn[conv][co][p][c] i8 = sign(w - mean); SC4 = (alpha, scale, shift, 0)
// with IEEE ops in the reference's exact order.
// ---------------------------------------------------------------------------
__global__ void prep_weights(const float* __restrict__ w1, const float* __restrict__ w2,
                             const float* __restrict__ a1, const float* __restrict__ g1,
                             const float* __restrict__ b1, const float* __restrict__ m1,
                             const float* __restrict__ v1,
                             const float* __restrict__ a2, const float* __restrict__ g2,
                             const float* __restrict__ b2, const float* __restrict__ m2,
                             const float* __restrict__ v2,
                             unsigned char* __restrict__ Wsgn, float4* __restrict__ SC4)
{
    const int co   = blockIdx.x;
    const int conv = blockIdx.y;
    const int c    = threadIdx.x;
    const float* w = conv ? w2 : w1;

    float wv[9];
    const float* wp = w + ((size_t)co * 256 + c) * 9;
    float s = 0.f;
#pragma unroll
    for (int p = 0; p < 9; ++p) { wv[p] = wp[p]; s += wv[p]; }

    __shared__ float red[256];
    red[c] = s;
    __syncthreads();
    for (int off = 128; off > 0; off >>= 1) {
        if (c < off) red[c] += red[c + off];
        __syncthreads();
    }
    const float mean = __fdiv_rn(red[0], 2304.0f);

    unsigned char* wrow = Wsgn + ((size_t)(conv * 256 + co) * 9) * 256;
#pragma unroll
    for (int p = 0; p < 9; ++p)
        wrow[p * 256 + c] = (wv[p] > mean) ? 0x01u : 0xFFu;

    if (c == 0) {
        const float alpha = conv ? a2[co] : a1[co];
        const float gamma = conv ? g2[co] : g1[co];
        const float beta  = conv ? b2[co] : b1[co];
        const float mu    = conv ? m2[co] : m1[co];
        const float var   = conv ? v2[co] : v1[co];
        const float sq    = __fsqrt_rn(__fadd_rn(var, EPSV));
        const float scale = __fdiv_rn(gamma, sq);
        const float shift = __fsub_rn(beta, __fdiv_rn(__fmul_rn(mu, gamma), sq));
        SC4[conv * 256 + co] = make_float4(alpha, scale, shift, 0.f);
    }
}

// ---------------------------------------------------------------------------
// Kernel 2: B fragments in exact mfma_i32_32x32x32_i8 operand order.
// Frag f = conv*576 + g*72 + p*8 + cb. Lane l: B[k=(l>>5)*16+j][n=l&31].
// ---------------------------------------------------------------------------
__global__ void build_bfrag(const unsigned char* __restrict__ Wsgn, uint4* __restrict__ Bf)
{
    const int f    = blockIdx.x;           // 0..1151
    const int lane = threadIdx.x;          // 0..63
    const int conv = f / 576;
    const int rem  = f % 576;
    const int g    = rem / 72;
    const int p    = (rem % 72) / 8;
    const int cb   = rem % 8;
    const int co   = g * 32 + (lane & 31);
    const unsigned char* src = Wsgn + ((size_t)(conv * 256 + co) * 9 + p) * 256
                                    + cb * 32 + (lane >> 5) * 16;
    Bf[(size_t)f * 64 + lane] = *(const uint4*)src;
}

// ---------------------------------------------------------------------------
// Kernel 3: binarize x -> packed bits. A[n][pixel][j], j = chan/32.
// ---------------------------------------------------------------------------
__global__ void binarize_x(const float* __restrict__ x, u32* __restrict__ A1)
{
    const int n = blockIdx.x >> 3;
    const int j = blockIdx.x & 7;
    const int p = threadIdx.x;
    const float* xp = x + (((size_t)n * 256 + j * 32) * 1024) + p;
    u32 bits = 0;
#pragma unroll
    for (int k = 0; k < 32; ++k) {
        float v = xp[(size_t)k * 1024];
        bits |= (v > 0.f ? 1u : 0u) << k;
    }
    A1[((size_t)n * 1024 + p) * 8 + j] = bits;
}

__device__ __forceinline__ u32 expand4(u32 x)
{
    u32 r;
    r  = ((x & 1u) ? 0x00000001u : 0x000000FFu);
    r |= ((x & 2u) ? 0x00000100u : 0x0000FF00u);
    r |= ((x & 4u) ? 0x00010000u : 0x00FF0000u);
    r |= ((x & 8u) ? 0x01000000u : 0xFF000000u);
    return r;
}

// ---------------------------------------------------------------------------
// Kernel 4/5: binary conv as i8 MFMA GEMM — sched_barrier-pinned pipeline.
// Block: 256 thr = 4 waves; 2 output rows x 32 cols x ALL 256 cos.
// Wave w: co-groups g0=2w, g1=2w+1, rows y0,y0+1 -> 4 v16i accs (AGPRs).
// Grid: 64 n x 16 ypairs = 1024 blocks; LDS 34,816 B.
//
// R10 lesson: SSA-level double-buffering alone is DEFEATED by the machine
// scheduler — it sank the prefetch loads back to their uses (VGPR stayed
// 52, dur unchanged 69us, MfmaUtil 22%). Fix: pin the phase order with
// __builtin_amdgcn_sched_barrier(0) fences:
//   {issue O loads} |SB| {setprio1; 16 MFMA on E; setprio0} |SB|
//   {issue E loads} |SB| {setprio1; 16 MFMA on O; setprio0} |SB|
// Loads for step k+1 now issue BEFORE step k's MFMA cluster in program
// order -> waitcnt pass emits counted waits (vmcnt(4)/lgkmcnt(4), never
// 0 mid-loop) and RA must keep both sets live. T5 setprio arbitrates for
// the MFMA-entering wave. Prefetch overrun at step 36 lands in the mapped
// ws gap after Bf.
//
// LDS act tile [c16 0..15][r 0..3][xs 0..33], 16B cells. granule%8 = xs%8
// -> ds_read_b128 conflict-free (R6-R10 verified: SQ_LDS_BANK_CONFLICT=0).
// Step k: p=k>>2 (dy=p/3, dx=p%3), cbpair=k&3;
//   dso = labase + dy*544 + dx*16 + cbpair*8704; B advances 128 v4i/step.
//
// A: m(=x)=l&31, k=(l>>5)*16+j ; B: n(=co)=l&31 ; C/D: n=l&31,
// m=(reg&3)+8*(reg>>2)+4*(l>>5)   [R5-R10 HW-verified].
//
// CONV==1: t=(dot*alpha)*scale+shift; packed sign bits via __ballot.
// CONV==2: per-row LDS transpose ep[x][co] (pad 257) -> coalesced
//          clamp(t + X) float4 stores.
// ---------------------------------------------------------------------------
template<int CONV>
__global__ __launch_bounds__(256, 3)
void conv_mfma(const u32* __restrict__ A_in, const v4i* __restrict__ Bf,
               const float4* __restrict__ SC4, const float* __restrict__ X,
               u32* __restrict__ A_out, float* __restrict__ OUT)
{
    const int n    = blockIdx.x >> 4;
    const int yp   = blockIdx.x & 15;
    const int y0   = yp * 2;
    const int tid  = threadIdx.x;
    const int wave = tid >> 6;
    const int lane = tid & 63;

    __shared__ alignas(16) unsigned char lds[34816];

    // ---- stage: packed bits -> i8 tile [c16][r][xs], halo -> 0 ----
    for (int s = tid; s < 2176; s += 256) {
        const int xs   = s % 34;
        const int rest = s / 34;
        const int r    = rest & 3;          // tile row (image row y0-1+r)
        const int c16  = rest >> 2;         // 16-channel group
        const int iy   = y0 - 1 + r;
        const int ix   = xs - 1;
        u32 d0 = 0, d1 = 0, d2 = 0, d3 = 0;
        if ((unsigned)iy < 32u && (unsigned)ix < 32u) {
            const u32 wrd = A_in[((size_t)n * 1024 + iy * 32 + ix) * 8 + (c16 >> 1)];
            const u32 h = (wrd >> ((c16 & 1) * 16)) & 0xFFFFu;
            d0 = expand4(h);
            d1 = expand4(h >> 4);
            d2 = expand4(h >> 8);
            d3 = expand4(h >> 12);
        }
        *(uint4*)(lds + (size_t)s * 16) = make_uint4(d0, d1, d2, d3);
    }
    __syncthreads();

    const v16i Z = {0,0,0,0,0,0,0,0,0,0,0,0,0,0,0,0};
    const v4i  Z4 = {0,0,0,0};
    v16i acc00 = Z, acc01 = Z;   // row y0   x {g0, g1}
    v16i acc10 = Z, acc11 = Z;   // row y0+1 x {g0, g1}

    const int g0 = wave * 2, g1 = g0 + 1;
    const v4i* bp0 = Bf + ((size_t)(((CONV == 2) ? 576 : 0) + g0 * 72)) * 64 + lane;
    const v4i* bp1 = Bf + ((size_t)(((CONV == 2) ? 576 : 0) + g1 * 72)) * 64 + lane;
    const u32 labase = (u32)((lane >> 5) * 2176 + (lane & 31) * 16);

#define SB  __builtin_amdgcn_sched_barrier(0)

#define DSOFF(K)                                                                \
    (labase + (u32)((((K) >> 2) / 3) * 544 + (((K) >> 2) % 3) * 16              \
                    + ((K) & 3) * 8704))

#define PREFB(S0A, S0B, S1A, S1B, IDX)                                          \
    S0A = bp0[(IDX) * 128];   S0B = bp0[(IDX) * 128 + 64];                      \
    S1A = bp1[(IDX) * 128];   S1B = bp1[(IDX) * 128 + 64];

#define PREFA(A0, A1, A2, A3, DSO)                                              \
    A0 = *(const v4i*)(lds + (DSO));                                            \
    A1 = *(const v4i*)(lds + (DSO) + 544);                                      \
    A2 = *(const v4i*)(lds + (DSO) + 4352);                                     \
    A3 = *(const v4i*)(lds + (DSO) + 4896);

#define DOMFMA(A0, A1, A2, A3, B0A, B0B, B1A, B1B)                              \
    acc00 = __builtin_amdgcn_mfma_i32_32x32x32_i8(A0, B0A, acc00, 0, 0, 0);     \
    acc01 = __builtin_amdgcn_mfma_i32_32x32x32_i8(A0, B1A, acc01, 0, 0, 0);     \
    acc10 = __builtin_amdgcn_mfma_i32_32x32x32_i8(A1, B0A, acc10, 0, 0, 0);     \
    acc11 = __builtin_amdgcn_mfma_i32_32x32x32_i8(A1, B1A, acc11, 0, 0, 0);     \
    acc00 = __builtin_amdgcn_mfma_i32_32x32x32_i8(A2, B0B, acc00, 0, 0, 0);     \
    acc01 = __builtin_amdgcn_mfma_i32_32x32x32_i8(A2, B1B, acc01, 0, 0, 0);     \
    acc10 = __builtin_amdgcn_mfma_i32_32x32x32_i8(A3, B0B, acc10, 0, 0, 0);     \
    acc11 = __builtin_amdgcn_mfma_i32_32x32x32_i8(A3, B1B, acc11, 0, 0, 0);

    // two alternating register sets (mutable, named -> stay in VGPRs)
    v4i ea0 = Z4, ea1 = Z4, ea2 = Z4, ea3 = Z4;
    v4i eb0a = Z4, eb0b = Z4, eb1a = Z4, eb1b = Z4;
    v4i oa0 = Z4, oa1 = Z4, oa2 = Z4, oa3 = Z4;
    v4i ob0a = Z4, ob0b = Z4, ob1a = Z4, ob1b = Z4;

    // prologue: step 0 -> set E
    PREFB(eb0a, eb0b, eb1a, eb1b, 0)
    PREFA(ea0, ea1, ea2, ea3, DSOFF(0))

#pragma unroll 1
    for (int k2 = 0; k2 < 18; ++k2) {
        const int k = k2 * 2;
        // phase 1: issue step-(k+1) loads -> O
        PREFB(ob0a, ob0b, ob1a, ob1b, 1)
        PREFA(oa0, oa1, oa2, oa3, DSOFF(k + 1))
        SB;
        // phase 2: MFMA cluster on E (auto-waitcnt: counted, not 0)
        __builtin_amdgcn_s_setprio(1);
        DOMFMA(ea0, ea1, ea2, ea3, eb0a, eb0b, eb1a, eb1b)
        __builtin_amdgcn_s_setprio(0);
        SB;
        // phase 3: issue step-(k+2) loads -> E
        PREFB(eb0a, eb0b, eb1a, eb1b, 2)
        PREFA(ea0, ea1, ea2, ea3, DSOFF(k + 2))
        SB;
        // phase 4: MFMA cluster on O
        __builtin_amdgcn_s_setprio(1);
        DOMFMA(oa0, oa1, oa2, oa3, ob0a, ob0b, ob1a, ob1b)
        __builtin_amdgcn_s_setprio(0);
        SB;

        bp0 += 256; bp1 += 256;
    }
#undef DSOFF
#undef PREFB
#undef PREFA
#undef DOMFMA
#undef SB

    const int col = lane & 31;
    const float4 sc0 = SC4[((CONV == 2) ? 256 : 0) + g0 * 32 + col];
    const float4 sc1 = SC4[((CONV == 2) ? 256 : 0) + g1 * 32 + col];

    if (CONV == 1) {
#define EP1(ACC, RY, G, SC)                                                     \
        { _Pragma("unroll")                                                     \
          for (int reg = 0; reg < 16; ++reg) {                                  \
              const float t = __fadd_rn(__fmul_rn(__fmul_rn((float)ACC[reg],    \
                                        SC.x), SC.y), SC.z);                    \
              const u64 m = __ballot(t > 0.f);                                  \
              if (lane == 0) {                                                  \
                  const int x = (reg & 3) + 8 * (reg >> 2);                     \
                  const size_t pb = (size_t)n * 1024 + (y0 + (RY)) * 32 + x;    \
                  A_out[pb * 8 + (G)]       = (u32)m;                           \
                  A_out[(pb + 4) * 8 + (G)] = (u32)(m >> 32);                   \
              } } }
        EP1(acc00, 0, g0, sc0)  EP1(acc01, 0, g1, sc1)
        EP1(acc10, 1, g0, sc0)  EP1(acc11, 1, g1, sc1)
#undef EP1
    } else {
        __syncthreads();                    // act tile reads done
        float* ep = (float*)lds;            // ep[x][co] pad 257 = 32.9 KB
#define EP2PASS(A0, A1, RY)                                                     \
        { _Pragma("unroll")                                                     \
          for (int reg = 0; reg < 16; ++reg) {                                  \
              const int x = (reg & 3) + 8 * (reg >> 2) + 4 * (lane >> 5);       \
              const float t0 = __fadd_rn(__fmul_rn(__fmul_rn((float)A0[reg],    \
                                         sc0.x), sc0.y), sc0.z);                \
              const float t1 = __fadd_rn(__fmul_rn(__fmul_rn((float)A1[reg],    \
                                         sc1.x), sc1.y), sc1.z);                \
              ep[x * 257 + g0 * 32 + col] = t0;                                 \
              ep[x * 257 + g1 * 32 + col] = t1;                                 \
          }                                                                     \
          __syncthreads();                                                      \
          {                                                                     \
              const int co = tid;                                               \
              const size_t gb = ((size_t)(n * 256 + co)) * 1024                 \
                              + (y0 + (RY)) * 32;                               \
              _Pragma("unroll")                                                 \
              for (int x4 = 0; x4 < 32; x4 += 4) {                              \
                  float4 r;                                                     \
                  r.x = ep[(x4 + 0) * 257 + co];                                \
                  r.y = ep[(x4 + 1) * 257 + co];                                \
                  r.z = ep[(x4 + 2) * 257 + co];                                \
                  r.w = ep[(x4 + 3) * 257 + co];                                \
                  const float4 xv = *(const float4*)(X + gb + x4);              \
                  r.x = fminf(1.f, fmaxf(-1.f, __fadd_rn(r.x, xv.x)));          \
                  r.y = fminf(1.f, fmaxf(-1.f, __fadd_rn(r.y, xv.y)));          \
                  r.z = fminf(1.f, fmaxf(-1.f, __fadd_rn(r.z, xv.z)));          \
                  r.w = fminf(1.f, fmaxf(-1.f, __fadd_rn(r.w, xv.w)));          \
                  *(float4*)(OUT + gb + x4) = r;                                \
              }                                                                 \
          }                                                                     \
          __syncthreads(); }
        EP2PASS(acc00, acc01, 0)
        EP2PASS(acc10, acc11, 1)
#undef EP2PASS
    }
}

// ---------------------------------------------------------------------------
extern "C" void kernel_launch(void* const* d_in, const int* in_sizes, int n_in,
                              void* d_out, int out_size, void* d_ws, size_t ws_size,
                              hipStream_t stream)
{
    const float* x   = (const float*)d_in[0];
    const float* w1  = (const float*)d_in[1];
    const float* al1 = (const float*)d_in[2];
    const float* g1  = (const float*)d_in[3];
    const float* b1  = (const float*)d_in[4];
    const float* m1  = (const float*)d_in[5];
    const float* v1  = (const float*)d_in[6];
    const float* w2  = (const float*)d_in[7];
    const float* al2 = (const float*)d_in[8];
    const float* g2  = (const float*)d_in[9];
    const float* b2  = (const float*)d_in[10];
    const float* m2  = (const float*)d_in[11];
    const float* v2  = (const float*)d_in[12];
    float* out = (float*)d_out;

    char* ws = (char*)d_ws;
    float4*        SC4  = (float4*)(ws);                        //   8 KB
    unsigned char* Wsgn = (unsigned char*)(ws + (64u << 10));   // 1.18 MB
    uint4*         Bf   = (uint4*)(ws + (2u << 20));            // 1.18 MB (+overrun gap)
    u32*           A1   = (u32*)(ws + (4u << 20));              // 2 MB
    u32*           A2   = (u32*)(ws + (6u << 20));              // 2 MB
    (void)ws_size; (void)in_sizes; (void)n_in; (void)out_size;

    prep_weights<<<dim3(256, 2), 256, 0, stream>>>(w1, w2, al1, g1, b1, m1, v1,
                                                   al2, g2, b2, m2, v2, Wsgn, SC4);
    build_bfrag<<<dim3(1152), 64, 0, stream>>>(Wsgn, Bf);
    binarize_x<<<dim3(512), 1024, 0, stream>>>(x, A1);
    conv_mfma<1><<<dim3(1024), 256, 0, stream>>>(A1, (const v4i*)Bf, SC4,
                                                 nullptr, A2, nullptr);
    conv_mfma<2><<<dim3(1024), 256, 0, stream>>>(A2, (const v4i*)Bf, SC4,
                                                 x, nullptr, out);
}

// Round 12
// 124.398 us; speedup vs baseline: 1.0786x; 1.0786x over previous
//
#include <hip/hip_runtime.h>
#include <cstdint>
#include <cstddef>

using u32 = unsigned int;
using u64 = unsigned long long;

typedef int v4i  __attribute__((ext_vector_type(4)));
typedef int v16i __attribute__((ext_vector_type(16)));

#define EPSV 1e-5f

// ---------------------------------------------------------------------------
// Kernel 1: weight prep. One block per (co, conv). 256 threads = 256 in-chans.
// Wsgn[conv][co][p][c] i8 = sign(w - mean); SC4 = (alpha, scale, shift, 0)
// with IEEE ops in the reference's exact order.
// ---------------------------------------------------------------------------
__global__ void prep_weights(const float* __restrict__ w1, const float* __restrict__ w2,
                             const float* __restrict__ a1, const float* __restrict__ g1,
                             const float* __restrict__ b1, const float* __restrict__ m1,
                             const float* __restrict__ v1,
                             const float* __restrict__ a2, const float* __restrict__ g2,
                             const float* __restrict__ b2, const float* __restrict__ m2,
                             const float* __restrict__ v2,
                             unsigned char* __restrict__ Wsgn, float4* __restrict__ SC4)
{
    const int co   = blockIdx.x;
    const int conv = blockIdx.y;
    const int c    = threadIdx.x;
    const float* w = conv ? w2 : w1;

    float wv[9];
    const float* wp = w + ((size_t)co * 256 + c) * 9;
    float s = 0.f;
#pragma unroll
    for (int p = 0; p < 9; ++p) { wv[p] = wp[p]; s += wv[p]; }

    __shared__ float red[256];
    red[c] = s;
    __syncthreads();
    for (int off = 128; off > 0; off >>= 1) {
        if (c < off) red[c] += red[c + off];
        __syncthreads();
    }
    const float mean = __fdiv_rn(red[0], 2304.0f);

    unsigned char* wrow = Wsgn + ((size_t)(conv * 256 + co) * 9) * 256;
#pragma unroll
    for (int p = 0; p < 9; ++p)
        wrow[p * 256 + c] = (wv[p] > mean) ? 0x01u : 0xFFu;

    if (c == 0) {
        const float alpha = conv ? a2[co] : a1[co];
        const float gamma = conv ? g2[co] : g1[co];
        const float beta  = conv ? b2[co] : b1[co];
        const float mu    = conv ? m2[co] : m1[co];
        const float var   = conv ? v2[co] : v1[co];
        const float sq    = __fsqrt_rn(__fadd_rn(var, EPSV));
        const float scale = __fdiv_rn(gamma, sq);
        const float shift = __fsub_rn(beta, __fdiv_rn(__fmul_rn(mu, gamma), sq));
        SC4[conv * 256 + co] = make_float4(alpha, scale, shift, 0.f);
    }
}

// ---------------------------------------------------------------------------
// Kernel 2: B fragments in exact mfma_i32_32x32x32_i8 operand order.
// Frag f = conv*576 + g*72 + p*8 + cb. Lane l: B[k=(l>>5)*16+j][n=l&31].
// ---------------------------------------------------------------------------
__global__ void build_bfrag(const unsigned char* __restrict__ Wsgn, uint4* __restrict__ Bf)
{
    const int f    = blockIdx.x;           // 0..1151
    const int lane = threadIdx.x;          // 0..63
    const int conv = f / 576;
    const int rem  = f % 576;
    const int g    = rem / 72;
    const int p    = (rem % 72) / 8;
    const int cb   = rem % 8;
    const int co   = g * 32 + (lane & 31);
    const unsigned char* src = Wsgn + ((size_t)(conv * 256 + co) * 9 + p) * 256
                                    + cb * 32 + (lane >> 5) * 16;
    Bf[(size_t)f * 64 + lane] = *(const uint4*)src;
}

// ---------------------------------------------------------------------------
// Kernel 3: binarize x -> packed bits. A[n][pixel][j], j = chan/32.
// ---------------------------------------------------------------------------
__global__ void binarize_x(const float* __restrict__ x, u32* __restrict__ A1)
{
    const int n = blockIdx.x >> 3;
    const int j = blockIdx.x & 7;
    const int p = threadIdx.x;
    const float* xp = x + (((size_t)n * 256 + j * 32) * 1024) + p;
    u32 bits = 0;
#pragma unroll
    for (int k = 0; k < 32; ++k) {
        float v = xp[(size_t)k * 1024];
        bits |= (v > 0.f ? 1u : 0u) << k;
    }
    A1[((size_t)n * 1024 + p) * 8 + j] = bits;
}

__device__ __forceinline__ u32 expand4(u32 x)
{
    u32 r;
    r  = ((x & 1u) ? 0x00000001u : 0x000000FFu);
    r |= ((x & 2u) ? 0x00000100u : 0x0000FF00u);
    r |= ((x & 4u) ? 0x00010000u : 0x00FF0000u);
    r |= ((x & 8u) ? 0x01000000u : 0xFF000000u);
    return r;
}

// ---------------------------------------------------------------------------
// Kernel 4/5: binary conv as i8 MFMA GEMM — 4-row tile, 4-deep B pipeline.
// Block: 256 thr = 4 waves; 4 output rows x 32 cols x ALL 256 cos (M=128).
// Wave w: groups g0=2w,g1=2w+1 x 4 rows -> 8 v16i accs (128 AGPR).
// Grid: 64 n x 8 yquads = 512 blocks = exactly 2/CU, no tail.
//
// R11 lesson: 1-step prefetch (293 cyc cover) left MfmaUtil at 22% — B L2
// latency under lockstep burst exceeds one MFMA-cluster. This version:
//  (a) M=128/block halves B traffic per MFMA (576KB panel amortized over
//      2304 MFMAs: 64 B/MFMA; 295 MB/conv ~ 8.5us L2);
//  (b) FOUR named B register pairs cycle refill-after-use -> each B load
//      is ~3 MFMA clusters (~900 cyc) ahead of its consumer wait;
//  (c) A stays 1-step ahead (LDS ~120cyc << 293cyc cluster).
// All sets are named scalars in a rolled (unroll 1), SB-fenced loop —
// the structure R10/R11 proved spill-free.
//
// LDS act tile [c16 0..15][r 0..5][xs 0..33], 16B cells = 52,224 B.
// granule%8 = xs%8 -> ds_read_b128 conflict-free (R6-R11: 0 conflicts).
// Step k (0..71): p=k>>3 (dy=p/3,dx=p%3), cb=k&7;
//   dso = labase + cb*6528 + dy*544 + dx*16; rows at +0/544/1088/1632.
// Overruns (A: k=72,73 / B: frags +3 past end) land in mapped lds/ws gap.
//
// A: m(=x)=l&31, k=(l>>5)*16+j ; B: n(=co)=l&31 ; C/D: n=l&31,
// m=(reg&3)+8*(reg>>2)+4*(l>>5)   [R5-R11 HW-verified].
//
// CONV==1: t=(dot*alpha)*scale+shift; packed sign bits via __ballot.
// CONV==2: per-row LDS transpose ep[x][co] (pad 257) -> coalesced
//          clamp(t + X) float4 stores.
// ---------------------------------------------------------------------------
template<int CONV>
__global__ __launch_bounds__(256, 2)
void conv_mfma(const u32* __restrict__ A_in, const v4i* __restrict__ Bf,
               const float4* __restrict__ SC4, const float* __restrict__ X,
               u32* __restrict__ A_out, float* __restrict__ OUT)
{
    const int n    = blockIdx.x >> 3;
    const int yq   = blockIdx.x & 7;
    const int y0   = yq * 4;
    const int tid  = threadIdx.x;
    const int wave = tid >> 6;
    const int lane = tid & 63;

    __shared__ alignas(16) unsigned char lds[52224];

    const int g0 = wave * 2, g1 = g0 + 1;
    const v4i* bp0 = Bf + ((size_t)(((CONV == 2) ? 576 : 0) + g0 * 72)) * 64 + lane;
    const v4i* bp1 = Bf + ((size_t)(((CONV == 2) ? 576 : 0) + g1 * 72)) * 64 + lane;

    // prologue B loads issued BEFORE staging (independent of LDS)
    v4i w00 = bp0[0],   w10 = bp1[0];
    v4i w01 = bp0[64],  w11 = bp1[64];
    v4i w02 = bp0[128], w12 = bp1[128];
    v4i w03 = bp0[192], w13 = bp1[192];

    // ---- stage: packed bits -> i8 tile [c16][r 0..5][xs], halo -> 0 ----
    for (int s = tid; s < 3264; s += 256) {
        const int xs   = s % 34;
        const int rest = s / 34;
        const int r    = rest % 6;          // tile row (image row y0-1+r)
        const int c16  = rest / 6;          // 16-channel group
        const int iy   = y0 - 1 + r;
        const int ix   = xs - 1;
        u32 d0 = 0, d1 = 0, d2 = 0, d3 = 0;
        if ((unsigned)iy < 32u && (unsigned)ix < 32u) {
            const u32 wrd = A_in[((size_t)n * 1024 + iy * 32 + ix) * 8 + (c16 >> 1)];
            const u32 h = (wrd >> ((c16 & 1) * 16)) & 0xFFFFu;
            d0 = expand4(h);
            d1 = expand4(h >> 4);
            d2 = expand4(h >> 8);
            d3 = expand4(h >> 12);
        }
        *(uint4*)(lds + (size_t)s * 16) = make_uint4(d0, d1, d2, d3);
    }
    __syncthreads();

    const v16i Z = {0,0,0,0,0,0,0,0,0,0,0,0,0,0,0,0};
    const v4i  Z4 = {0,0,0,0};
    v16i acc00 = Z, acc01 = Z;   // row y0   x {g0,g1}
    v16i acc10 = Z, acc11 = Z;   // row y0+1
    v16i acc20 = Z, acc21 = Z;   // row y0+2
    v16i acc30 = Z, acc31 = Z;   // row y0+3

    const u32 labase = (u32)((lane >> 5) * 3264 + (lane & 31) * 16);

#define SB  __builtin_amdgcn_sched_barrier(0)

#define DSOFFK(K)                                                               \
    (labase + (u32)(((K) & 7) * 6528 + ((((K) >> 3)) / 3) * 544                 \
                    + ((((K) >> 3)) % 3) * 16))

#define PREFA(A0, A1, A2, A3, DSO)                                              \
    A0 = *(const v4i*)(lds + (DSO));                                            \
    A1 = *(const v4i*)(lds + (DSO) + 544);                                      \
    A2 = *(const v4i*)(lds + (DSO) + 1088);                                     \
    A3 = *(const v4i*)(lds + (DSO) + 1632);

#define MFMA8(A0, A1, A2, A3, W0, W1)                                           \
    acc00 = __builtin_amdgcn_mfma_i32_32x32x32_i8(A0, W0, acc00, 0, 0, 0);      \
    acc01 = __builtin_amdgcn_mfma_i32_32x32x32_i8(A0, W1, acc01, 0, 0, 0);      \
    acc10 = __builtin_amdgcn_mfma_i32_32x32x32_i8(A1, W0, acc10, 0, 0, 0);      \
    acc11 = __builtin_amdgcn_mfma_i32_32x32x32_i8(A1, W1, acc11, 0, 0, 0);      \
    acc20 = __builtin_amdgcn_mfma_i32_32x32x32_i8(A2, W0, acc20, 0, 0, 0);      \
    acc21 = __builtin_amdgcn_mfma_i32_32x32x32_i8(A2, W1, acc21, 0, 0, 0);      \
    acc30 = __builtin_amdgcn_mfma_i32_32x32x32_i8(A3, W0, acc30, 0, 0, 0);      \
    acc31 = __builtin_amdgcn_mfma_i32_32x32x32_i8(A3, W1, acc31, 0, 0, 0);

    // A double-buffer sets
    v4i ea0 = Z4, ea1 = Z4, ea2 = Z4, ea3 = Z4;
    v4i oa0 = Z4, oa1 = Z4, oa2 = Z4, oa3 = Z4;

    PREFA(ea0, ea1, ea2, ea3, DSOFFK(0))

#pragma unroll 1
    for (int k4 = 0; k4 < 18; ++k4) {
        const int kb = k4 * 4;
        // step 0: compute E/W0, prefetch A(kb+1)->O, refill W0<-frag kb+4
        PREFA(oa0, oa1, oa2, oa3, DSOFFK(kb + 1)) SB;
        __builtin_amdgcn_s_setprio(1);
        MFMA8(ea0, ea1, ea2, ea3, w00, w10)
        __builtin_amdgcn_s_setprio(0); SB;
        w00 = bp0[4 * 64]; w10 = bp1[4 * 64]; SB;
        // step 1: compute O/W1, prefetch A(kb+2)->E, refill W1<-frag kb+5
        PREFA(ea0, ea1, ea2, ea3, DSOFFK(kb + 2)) SB;
        __builtin_amdgcn_s_setprio(1);
        MFMA8(oa0, oa1, oa2, oa3, w01, w11)
        __builtin_amdgcn_s_setprio(0); SB;
        w01 = bp0[5 * 64]; w11 = bp1[5 * 64]; SB;
        // step 2: compute E/W2, prefetch A(kb+3)->O, refill W2<-frag kb+6
        PREFA(oa0, oa1, oa2, oa3, DSOFFK(kb + 3)) SB;
        __builtin_amdgcn_s_setprio(1);
        MFMA8(ea0, ea1, ea2, ea3, w02, w12)
        __builtin_amdgcn_s_setprio(0); SB;
        w02 = bp0[6 * 64]; w12 = bp1[6 * 64]; SB;
        // step 3: compute O/W3, prefetch A(kb+4)->E, refill W3<-frag kb+7
        PREFA(ea0, ea1, ea2, ea3, DSOFFK(kb + 4)) SB;
        __builtin_amdgcn_s_setprio(1);
        MFMA8(oa0, oa1, oa2, oa3, w03, w13)
        __builtin_amdgcn_s_setprio(0); SB;
        w03 = bp0[7 * 64]; w13 = bp1[7 * 64]; SB;

        bp0 += 256; bp1 += 256;
    }
#undef DSOFFK
#undef PREFA
#undef MFMA8
#undef SB

    const int col = lane & 31;
    const float4 sc0 = SC4[((CONV == 2) ? 256 : 0) + g0 * 32 + col];
    const float4 sc1 = SC4[((CONV == 2) ? 256 : 0) + g1 * 32 + col];

    if (CONV == 1) {
#define EP1(ACC, RY, G, SC)                                                     \
        { _Pragma("unroll")                                                     \
          for (int reg = 0; reg < 16; ++reg) {                                  \
              const float t = __fadd_rn(__fmul_rn(__fmul_rn((float)ACC[reg],    \
                                        SC.x), SC.y), SC.z);                    \
              const u64 m = __ballot(t > 0.f);                                  \
              if (lane == 0) {                                                  \
                  const int x = (reg & 3) + 8 * (reg >> 2);                     \
                  const size_t pb = (size_t)n * 1024 + (y0 + (RY)) * 32 + x;    \
                  A_out[pb * 8 + (G)]       = (u32)m;                           \
                  A_out[(pb + 4) * 8 + (G)] = (u32)(m >> 32);                   \
              } } }
        EP1(acc00, 0, g0, sc0)  EP1(acc01, 0, g1, sc1)
        EP1(acc10, 1, g0, sc0)  EP1(acc11, 1, g1, sc1)
        EP1(acc20, 2, g0, sc0)  EP1(acc21, 2, g1, sc1)
        EP1(acc30, 3, g0, sc0)  EP1(acc31, 3, g1, sc1)
#undef EP1
    } else {
        __syncthreads();                    // act tile reads done
        float* ep = (float*)lds;            // ep[x][co] pad 257 = 32.9 KB
#define EP2PASS(A0, A1, RY)                                                     \
        { _Pragma("unroll")                                                     \
          for (int reg = 0; reg < 16; ++reg) {                                  \
              const int x = (reg & 3) + 8 * (reg >> 2) + 4 * (lane >> 5);       \
              const float t0 = __fadd_rn(__fmul_rn(__fmul_rn((float)A0[reg],    \
                                         sc0.x), sc0.y), sc0.z);                \
              const float t1 = __fadd_rn(__fmul_rn(__fmul_rn((float)A1[reg],    \
                                         sc1.x), sc1.y), sc1.z);                \
              ep[x * 257 + g0 * 32 + col] = t0;                                 \
              ep[x * 257 + g1 * 32 + col] = t1;                                 \
          }                                                                     \
          __syncthreads();                                                      \
          {                                                                     \
              const int co = tid;                                               \
              const size_t gb = ((size_t)(n * 256 + co)) * 1024                 \
                              + (y0 + (RY)) * 32;                               \
              _Pragma("unroll")                                                 \
              for (int x4 = 0; x4 < 32; x4 += 4) {                              \
                  float4 r;                                                     \
                  r.x = ep[(x4 + 0) * 257 + co];                                \
                  r.y = ep[(x4 + 1) * 257 + co];                                \
                  r.z = ep[(x4 + 2) * 257 + co];                                \
                  r.w = ep[(x4 + 3) * 257 + co];                                \
                  const float4 xv = *(const float4*)(X + gb + x4);              \
                  r.x = fminf(1.f, fmaxf(-1.f, __fadd_rn(r.x, xv.x)));          \
                  r.y = fminf(1.f, fmaxf(-1.f, __fadd_rn(r.y, xv.y)));          \
                  r.z = fminf(1.f, fmaxf(-1.f, __fadd_rn(r.z, xv.z)));          \
                  r.w = fminf(1.f, fmaxf(-1.f, __fadd_rn(r.w, xv.w)));          \
                  *(float4*)(OUT + gb + x4) = r;                                \
              }                                                                 \
          }                                                                     \
          __syncthreads(); }
        EP2PASS(acc00, acc01, 0)
        EP2PASS(acc10, acc11, 1)
        EP2PASS(acc20, acc21, 2)
        EP2PASS(acc30, acc31, 3)
#undef EP2PASS
    }
}

// ---------------------------------------------------------------------------
extern "C" void kernel_launch(void* const* d_in, const int* in_sizes, int n_in,
                              void* d_out, int out_size, void* d_ws, size_t ws_size,
                              hipStream_t stream)
{
    const float* x   = (const float*)d_in[0];
    const float* w1  = (const float*)d_in[1];
    const float* al1 = (const float*)d_in[2];
    const float* g1  = (const float*)d_in[3];
    const float* b1  = (const float*)d_in[4];
    const float* m1  = (const float*)d_in[5];
    const float* v1  = (const float*)d_in[6];
    const float* w2  = (const float*)d_in[7];
    const float* al2 = (const float*)d_in[8];
    const float* g2  = (const float*)d_in[9];
    const float* b2  = (const float*)d_in[10];
    const float* m2  = (const float*)d_in[11];
    const float* v2  = (const float*)d_in[12];
    float* out = (float*)d_out;

    char* ws = (char*)d_ws;
    float4*        SC4  = (float4*)(ws);                        //   8 KB
    unsigned char* Wsgn = (unsigned char*)(ws + (64u << 10));   // 1.18 MB
    uint4*         Bf   = (uint4*)(ws + (2u << 20));            // 1.18 MB (+overrun gap)
    u32*           A1   = (u32*)(ws + (4u << 20));              // 2 MB
    u32*           A2   = (u32*)(ws + (6u << 20));              // 2 MB
    (void)ws_size; (void)in_sizes; (void)n_in; (void)out_size;

    prep_weights<<<dim3(256, 2), 256, 0, stream>>>(w1, w2, al1, g1, b1, m1, v1,
                                                   al2, g2, b2, m2, v2, Wsgn, SC4);
    build_bfrag<<<dim3(1152), 64, 0, stream>>>(Wsgn, Bf);
    binarize_x<<<dim3(512), 1024, 0, stream>>>(x, A1);
    conv_mfma<1><<<dim3(512), 256, 0, stream>>>(A1, (const v4i*)Bf, SC4,
                                                nullptr, A2, nullptr);
    conv_mfma<2><<<dim3(512), 256, 0, stream>>>(A2, (const v4i*)Bf, SC4,
                                                x, nullptr, out);
}